// Round 13
// baseline (337.578 us; speedup 1.0000x reference)
//
#include <hip/hip_runtime.h>
#include <hip/hip_bf16.h>

#define N_NODES 100000
#define DIM 64
#define SCAN_B 256

#define SCHUNKS 256         // edge chunks for bin scatter (full CU coverage)
#define BINSZ 512           // dst nodes per bin
#define NBINS 196           // ceil(N_NODES/BINSZ)

#define NBATCH 6250         // 100000 / 16 node-batches (exact)

typedef __attribute__((ext_vector_type(8))) short short8v;
typedef __attribute__((ext_vector_type(4))) float float4v;

// ---------------------------------------------------------------------------
// Degree count via global atomics (R13): 3.2M atomicAdds over 200K counters
// (800 KB, L2-resident; avg 16 hits/counter -> negligible contention).
// Replaces hist+reduce_norm and their 25.6 MB partials round-trip.
// NOT the R9 failure mode: that was ONE counter (GPU-wide serializer).
// ---------------------------------------------------------------------------
__global__ __launch_bounds__(256) void degree_kernel(
    const int* __restrict__ src, const int* __restrict__ dst, int E,
    int* __restrict__ odeg, int* __restrict__ ideg) {
  int stride = gridDim.x * 256;
  int E4 = E >> 2;
  const int4* s4 = (const int4*)src;
  const int4* d4 = (const int4*)dst;
  for (int i = blockIdx.x * 256 + threadIdx.x; i < E4; i += stride) {
    int4 sv = s4[i];
    int4 dv = d4[i];
    atomicAdd(&odeg[sv.x], 1); atomicAdd(&odeg[sv.y], 1);
    atomicAdd(&odeg[sv.z], 1); atomicAdd(&odeg[sv.w], 1);
    atomicAdd(&ideg[dv.x], 1); atomicAdd(&ideg[dv.y], 1);
    atomicAdd(&ideg[dv.z], 1); atomicAdd(&ideg[dv.w], 1);
  }
  for (int i = (E4 << 2) + blockIdx.x * 256 + threadIdx.x; i < E;
       i += stride) {
    atomicAdd(&odeg[src[i]], 1);
    atomicAdd(&ideg[dst[i]], 1);
  }
}

// ---------------------------------------------------------------------------
// xb[n][k] = bf16( x[n][k] * sn[n] )  — prescaled bf16 gather operand.
// ---------------------------------------------------------------------------
__global__ __launch_bounds__(256) void convert_prescale_kernel(
    const float* __restrict__ x, const float* __restrict__ sn,
    unsigned int* __restrict__ xb2, int nquads) {
  int i = blockIdx.x * 256 + threadIdx.x;
  if (i >= nquads) return;
  float s = sn[i >> 4];                       // node = (i*4)/64
  float4 v = ((const float4*)x)[i];
  __hip_bfloat162 a = __float22bfloat162_rn(make_float2(v.x * s, v.y * s));
  __hip_bfloat162 b = __float22bfloat162_rn(make_float2(v.z * s, v.w * s));
  unsigned int wa, wb;
  __builtin_memcpy(&wa, &a, 4);
  __builtin_memcpy(&wb, &b, 4);
  ((uint2*)xb2)[i] = make_uint2(wa, wb);
}

// ---------------------------------------------------------------------------
// Block-level exclusive scan of in-degree + norm computation (R13: norms
// folded in — this kernel reads ideg anyway; odeg read adds 0.4 MB).
// ---------------------------------------------------------------------------
__global__ __launch_bounds__(SCAN_B) void scan_block_kernel(
    const int* __restrict__ ideg, const int* __restrict__ odeg,
    float* __restrict__ sn, float* __restrict__ dn,
    int* __restrict__ out, int* __restrict__ bsum, int n) {
  __shared__ int s[SCAN_B];
  int t = threadIdx.x;
  int i = blockIdx.x * SCAN_B + t;
  int v = (i < n) ? ideg[i] : 0;
  if (i < n) {
    dn[i] = (v > 0) ? rsqrtf((float)v) : 0.0f;
    int o = odeg[i];
    sn[i] = (o > 0) ? rsqrtf((float)o) : 0.0f;
  }
  s[t] = v;
  __syncthreads();
  for (int off = 1; off < SCAN_B; off <<= 1) {
    int add = (t >= off) ? s[t - off] : 0;
    __syncthreads();
    s[t] += add;
    __syncthreads();
  }
  if (i < n) out[i] = s[t] - v;
  if (t == SCAN_B - 1) bsum[blockIdx.x] = s[t];
}

// ---------------------------------------------------------------------------
// Fused top-scan + add (R13): each block re-scans the 391 block sums in LDS
// (512 ints), then applies the prefix. Removes the scan_top launch.
// ---------------------------------------------------------------------------
__global__ __launch_bounds__(512) void scan_add_kernel(
    int* __restrict__ out, const int* __restrict__ bsum, int nb, int n,
    int total) {
  __shared__ int s[512];
  __shared__ int ex[512];
  int t = threadIdx.x;
  int v = (t < nb) ? bsum[t] : 0;
  s[t] = v;
  __syncthreads();
  for (int off = 1; off < 512; off <<= 1) {
    int add = (t >= off) ? s[t - off] : 0;
    __syncthreads();
    s[t] += add;
    __syncthreads();
  }
  ex[t] = s[t] - v;
  __syncthreads();
  int i = blockIdx.x * 512 + t;
  if (i < n) out[i] += ex[i >> 8];          // SCAN_B == 256
  if (i == 0) out[n] = total;
}

// ---------------------------------------------------------------------------
// Partition edges into NBINS dst-bins (R12-verified: 512 thr, int4 loads).
// ---------------------------------------------------------------------------
__global__ __launch_bounds__(512) void bin_scatter_kernel(
    const int* __restrict__ src, const int* __restrict__ dst,
    const int* __restrict__ offsets, int* __restrict__ bin_cursor,
    int2* __restrict__ binned, int E) {
  __shared__ int cnt[NBINS];
  __shared__ int base[NBINS];
  int t = threadIdx.x;
  for (int i = t; i < NBINS; i += 512) cnt[i] = 0;
  __syncthreads();
  int per = (((E + SCHUNKS - 1) / SCHUNKS) + 3) & ~3;   // 6252 for E=1.6M
  int beg = blockIdx.x * per;
  int end = min(beg + per, E);
  int n4 = (end > beg) ? ((end - beg) >> 2) : 0;
  const int4* d4 = (const int4*)(dst + beg);
  const int4* s4 = (const int4*)(src + beg);
  for (int i = t; i < n4; i += 512) {
    int4 dv = d4[i];
    atomicAdd(&cnt[dv.x >> 9], 1);
    atomicAdd(&cnt[dv.y >> 9], 1);
    atomicAdd(&cnt[dv.z >> 9], 1);
    atomicAdd(&cnt[dv.w >> 9], 1);
  }
  for (int i = beg + (n4 << 2) + t; i < end; i += 512)
    atomicAdd(&cnt[dst[i] >> 9], 1);
  __syncthreads();
  for (int i = t; i < NBINS; i += 512) {
    base[i] = offsets[i << 9] + atomicAdd(&bin_cursor[i], cnt[i]);
    cnt[i] = 0;
  }
  __syncthreads();
  for (int i = t; i < n4; i += 512) {
    int4 sv = s4[i];
    int4 dv = d4[i];
    int b0 = dv.x >> 9, r0 = atomicAdd(&cnt[b0], 1);
    binned[base[b0] + r0] = make_int2(sv.x, dv.x);
    int b1 = dv.y >> 9, r1 = atomicAdd(&cnt[b1], 1);
    binned[base[b1] + r1] = make_int2(sv.y, dv.y);
    int b2 = dv.z >> 9, r2 = atomicAdd(&cnt[b2], 1);
    binned[base[b2] + r2] = make_int2(sv.z, dv.z);
    int b3 = dv.w >> 9, r3 = atomicAdd(&cnt[b3], 1);
    binned[base[b3] + r3] = make_int2(sv.w, dv.w);
  }
  for (int i = beg + (n4 << 2) + t; i < end; i += 512) {
    int s = src[i], d = dst[i];
    int b = d >> 9;
    int r = atomicAdd(&cnt[b], 1);
    binned[base[b] + r] = make_int2(s, d);
  }
}

// ---------------------------------------------------------------------------
// CSR fill, one block per bin (R12-verified: 512 threads).
// ---------------------------------------------------------------------------
__global__ __launch_bounds__(512) void fill_binned_kernel(
    const int2* __restrict__ binned, const int* __restrict__ offsets,
    int* __restrict__ csr_src) {
  __shared__ int cur[BINSZ];
  __shared__ int offs[BINSZ];
  int b = blockIdx.x;
  int t = threadIdx.x;
  int lo = b << 9;
  for (int i = t; i < BINSZ; i += 512) {
    cur[i] = 0;
    offs[i] = offsets[min(lo + i, N_NODES)];
  }
  __syncthreads();
  int w0 = offsets[lo];
  int w1 = offsets[min(lo + BINSZ, N_NODES)];
  for (int e = w0 + t; e < w1; e += 512) {
    int2 sd = binned[e];
    int r = atomicAdd(&cur[sd.y - lo], 1);
    csr_src[offs[sd.y - lo] + r] = sd.x;
  }
}

// ---------------------------------------------------------------------------
// bf16 helpers (proven numerics).
// ---------------------------------------------------------------------------
__device__ __forceinline__ float bf_lo(unsigned int u) {
  unsigned int x = u << 16; float f; __builtin_memcpy(&f, &x, 4); return f;
}
__device__ __forceinline__ float bf_hi(unsigned int u) {
  unsigned int x = u & 0xffff0000u; float f; __builtin_memcpy(&f, &x, 4); return f;
}
__device__ __forceinline__ unsigned short bf16bits(float f) {
  __hip_bfloat16 h = __float2bfloat16(f);
  unsigned short u; __builtin_memcpy(&u, &h, 2); return u;
}
// (x,y) f32 -> packed hi bf16x2 (truncated) + packed lo bf16x2 (residual, RNE)
__device__ __forceinline__ void cvt_pair_hl(float x, float y,
                                            unsigned int& hi, unsigned int& lo) {
  unsigned int u0, u1;
  __builtin_memcpy(&u0, &x, 4);
  __builtin_memcpy(&u1, &y, 4);
  unsigned int h0 = u0 & 0xffff0000u, h1 = u1 & 0xffff0000u;
  hi = (h0 >> 16) | h1;
  float hf0, hf1;
  __builtin_memcpy(&hf0, &h0, 4);
  __builtin_memcpy(&hf1, &h1, 4);
  __hip_bfloat162 l2 = __float22bfloat162_rn(make_float2(x - hf0, y - hf1));
  __builtin_memcpy(&lo, &l2, 4);
}

// ---------------------------------------------------------------------------
// Pre-stage W as hi/lo bf16 B-fragments into GLOBAL (16 KiB per table).
// Layout: entry e = ((hl*4 + nt)*2 + kt)*64 + lane, 8 shorts each.
// k = kt*32 + (lane>>4)*8 + j, c = nt*16 + (lane&15)  (proven layout).
// Block 0 -> W1 table, block 1 -> W2 table.
// ---------------------------------------------------------------------------
__global__ __launch_bounds__(256) void stage_wfrag_kernel(
    const float* __restrict__ W1, const float* __restrict__ W2,
    short* __restrict__ Wg) {
  const float* W = blockIdx.x ? W2 : W1;
  short* outp = Wg + blockIdx.x * 8192;
  int t = threadIdx.x;
  for (int e = t; e < 1024; e += 256) {
    int lidx = e & 63;
    int f = e >> 6;                       // 0..15
    int ktv = f & 1, ntv = (f >> 1) & 3, hl = f >> 3;
#pragma unroll
    for (int j = 0; j < 8; ++j) {
      int k = ktv * 32 + (lidx >> 4) * 8 + j;
      int c = ntv * 16 + (lidx & 15);
      float w = W[k * DIM + c];
      unsigned short hb = bf16bits(w);
      short val;
      if (hl == 0) {
        val = (short)hb;
      } else {
        unsigned int hx = (unsigned int)hb << 16;
        float hf; __builtin_memcpy(&hf, &hx, 4);
        val = (short)bf16bits(w - hf);
      }
      outp[e * 8 + j] = val;
    }
  }
}

// ---------------------------------------------------------------------------
// Fused layer v9 (champion, replay-stable: R7/R8/R11/R12 all passed): 256-thr
// blocks, wave per 16-node batch, grid-stride. BYTE-IDENTICAL to R12.
// ---------------------------------------------------------------------------
template <bool PRESCALE, typename OUT_T>
__device__ __forceinline__ void epilogue_nt(
    float4v acc, float bv, int nb16, int kq, int lane, float snb,
    OUT_T* __restrict__ out, int nt) {
  int col = nt * 16 + (lane & 15);
#pragma unroll
  for (int r = 0; r < 4; ++r) {
    int node = nb16 + kq * 4 + r;          // C/D row = (lane>>4)*4 + reg
    float o = fmaxf(acc[r] + bv, 0.0f);
    if (PRESCALE) {
      o = o * __shfl(snb, kq * 4 + r);
      out[(long)node * DIM + col] = (OUT_T)__float2bfloat16(o);
    } else {
      out[(long)node * DIM + col] = (OUT_T)o;
    }
  }
}

template <bool PRESCALE, typename OUT_T>
__global__ __launch_bounds__(256, 4) void fused_layer_kernel(
    const __hip_bfloat16* __restrict__ xb, const int* __restrict__ csr_src,
    const int* __restrict__ offsets, const float* __restrict__ sn,
    const float* __restrict__ dn, const short* __restrict__ Wg,
    const float* __restrict__ bias, OUT_T* __restrict__ out, int N) {
  __shared__ __align__(16) float Astage[4][16][64];   // 16 KiB

  int t = threadIdx.x;
  int lane = t & 63;
  int wslot = t >> 6;          // 0..3
  int g = lane >> 4;           // edge sub-slot / MFMA k-group 0..3
  int q = lane & 15;           // feature quad / A-row (node-in-batch)

  float bias_nt[4];
#pragma unroll
  for (int nt = 0; nt < 4; ++nt) bias_nt[nt] = bias[nt * 16 + q];

  const uint2* __restrict__ xr = (const uint2*)xb;   // one row = 16 uint2
  const short8v* __restrict__ wfrag = (const short8v*)Wg;
  char* abase = (char*)&Astage[wslot][0][0];         // 256 B per node row

  int nwaves = gridDim.x * 4;
  for (int nb = blockIdx.x * 4 + wslot; nb < NBATCH; nb += nwaves) {
    asm volatile("" ::: "memory");   // no cross-batch hoist of W-frag loads
    int nb16 = nb * 16;
    int offv = offsets[nb16 + min(lane, 16)];
    float dnv = dn[nb16 + q];
    float snb = PRESCALE ? sn[nb16 + q] : 0.0f;

    // ---- gather 16 nodes (proven structure) ----
    for (int ni = 0; ni < 16; ++ni) {
      int beg = __shfl(offv, ni);
      int end = __shfl(offv, ni + 1);
      float a0 = 0.f, a1 = 0.f, a2 = 0.f, a3 = 0.f;
      for (int base = beg; base < end; base += 16) {
        int j0 = base + g;
        int jm = end - 1;
        bool p0 = j0 < end, p1 = j0 + 4 < end, p2 = j0 + 8 < end,
             p3 = j0 + 12 < end;
        int s0 = csr_src[min(j0, jm)];
        int s1 = csr_src[min(j0 + 4, jm)];
        int s2 = csr_src[min(j0 + 8, jm)];
        int s3 = csr_src[min(j0 + 12, jm)];
        uint2 v0 = make_uint2(0u, 0u), v1 = v0, v2 = v0, v3 = v0;
        if (p0) v0 = xr[(size_t)s0 * 16 + q];
        if (p1) v1 = xr[(size_t)s1 * 16 + q];
        if (p2) v2 = xr[(size_t)s2 * 16 + q];
        if (p3) v3 = xr[(size_t)s3 * 16 + q];
        a0 += bf_lo(v0.x); a1 += bf_hi(v0.x); a2 += bf_lo(v0.y); a3 += bf_hi(v0.y);
        a0 += bf_lo(v1.x); a1 += bf_hi(v1.x); a2 += bf_lo(v1.y); a3 += bf_hi(v1.y);
        a0 += bf_lo(v2.x); a1 += bf_hi(v2.x); a2 += bf_lo(v2.y); a3 += bf_hi(v2.y);
        a0 += bf_lo(v3.x); a1 += bf_hi(v3.x); a2 += bf_lo(v3.y); a3 += bf_hi(v3.y);
      }
      a0 += __shfl_xor(a0, 16); a1 += __shfl_xor(a1, 16);
      a2 += __shfl_xor(a2, 16); a3 += __shfl_xor(a3, 16);
      a0 += __shfl_xor(a0, 32); a1 += __shfl_xor(a1, 32);
      a2 += __shfl_xor(a2, 32); a3 += __shfl_xor(a3, 32);

      float dnw = __shfl(dnv, ni);
      if (lane < 16) {
        // quad q of node ni at swizzled slot (both sides use same involution)
        int woff = ni * 256 + ((lane * 16) ^ ((ni & 15) << 4));
        *(float4*)(abase + woff) =
            make_float4(a0 * dnw, a1 * dnw, a2 * dnw, a3 * dnw);
      }
    }

    // ---- project: read A rows (same-wave LDS, lgkm-ordered), 24 MFMA ----
    float4v acc0 = {0.f, 0.f, 0.f, 0.f}, acc1 = acc0, acc2 = acc0, acc3 = acc0;
#pragma unroll
    for (int kt = 0; kt < 2; ++kt) {
      int o1 = kt * 128 + g * 32;     // feats kt*32+8g.. of node q
      float4 fa = *(const float4*)(abase + q * 256 + (o1 ^ (q << 4)));
      float4 fb = *(const float4*)(abase + q * 256 + ((o1 + 16) ^ (q << 4)));
      union { unsigned int w[4]; short8v v; } Uh, Ul;
      cvt_pair_hl(fa.x, fa.y, Uh.w[0], Ul.w[0]);
      cvt_pair_hl(fa.z, fa.w, Uh.w[1], Ul.w[1]);
      cvt_pair_hl(fb.x, fb.y, Uh.w[2], Ul.w[2]);
      cvt_pair_hl(fb.z, fb.w, Uh.w[3], Ul.w[3]);
      short8v ahi = Uh.v, alo = Ul.v;
#define PROJ_NT(NT, ACC)                                                      \
      {                                                                       \
        short8v bh = wfrag[(((NT) * 2) + kt) * 64 + lane];                    \
        short8v bl = wfrag[(((4 + (NT)) * 2) + kt) * 64 + lane];              \
        ACC = __builtin_amdgcn_mfma_f32_16x16x32_bf16(ahi, bh, ACC, 0, 0, 0); \
        ACC = __builtin_amdgcn_mfma_f32_16x16x32_bf16(alo, bh, ACC, 0, 0, 0); \
        ACC = __builtin_amdgcn_mfma_f32_16x16x32_bf16(ahi, bl, ACC, 0, 0, 0); \
      }
      PROJ_NT(0, acc0)
      PROJ_NT(1, acc1)
      PROJ_NT(2, acc2)
      PROJ_NT(3, acc3)
#undef PROJ_NT
    }

    float snbv = PRESCALE ? snb : 0.0f;
    epilogue_nt<PRESCALE, OUT_T>(acc0, bias_nt[0], nb16, g, lane, snbv, out, 0);
    epilogue_nt<PRESCALE, OUT_T>(acc1, bias_nt[1], nb16, g, lane, snbv, out, 1);
    epilogue_nt<PRESCALE, OUT_T>(acc2, bias_nt[2], nb16, g, lane, snbv, out, 2);
    epilogue_nt<PRESCALE, OUT_T>(acc3, bias_nt[3], nb16, g, lane, snbv, out, 3);
  }
}

extern "C" void kernel_launch(void* const* d_in, const int* in_sizes, int n_in,
                              void* d_out, int out_size, void* d_ws, size_t ws_size,
                              hipStream_t stream) {
  const float* x        = (const float*)d_in[0];
  const int*   edge_src = (const int*)d_in[1];
  const int*   edge_dst = (const int*)d_in[2];
  const float* W1       = (const float*)d_in[3];
  const float* b1       = (const float*)d_in[4];
  const float* W2       = (const float*)d_in[5];
  const float* b2       = (const float*)d_in[6];
  float* out = (float*)d_out;

  const int E = in_sizes[1];
  const int N = N_NODES;
  const int NB = (N + SCAN_B - 1) / SCAN_B;   // 391

  // Workspace (4B units), same footprint as champion. regionB time-shared:
  //   odeg (degree..scan_block) -> binned (bin_scatter..fill) -> h1b (layers)
  // ideg time-shared: degree counts (degree..scan_block) -> W frag tables.
  float* sn         = (float*)d_ws;                  // N
  float* dn         = sn + N;                        // N
  int*   ideg       = (int*)(dn + N);                // N
  int*   bin_cursor = ideg + N;                      // 256 (contiguous w/ ideg)
  int*   offsets    = bin_cursor + 256;              // N+1
  int*   bsum       = offsets + (N + 1);             // 512
  int*   csr_src    = bsum + 512;                    // E
  unsigned int* xb_raw = (unsigned int*)(csr_src + E);       // N*DIM/2 (12.8MB)
  unsigned int* regionB = xb_raw + (size_t)N * DIM / 2;      // 12.8MB
  int*   odeg     = (int*)regionB;                   // N (dead after scan_block)
  int2*  binned   = (int2*)regionB;                  // E int2
  __hip_bfloat16* xb  = (__hip_bfloat16*)xb_raw;
  __hip_bfloat16* h1b = (__hip_bfloat16*)regionB;
  short* Wg = (short*)ideg;                          // 2 x 8192 shorts (32 KB)

  // zero ideg + bin_cursor (contiguous) and odeg
  hipMemsetAsync(ideg, 0, (N + 256) * sizeof(int), stream);
  hipMemsetAsync(odeg, 0, N * sizeof(int), stream);

  // --- degrees via L2-resident global atomics (replaces hist+reduce) ---
  degree_kernel<<<1024, 256, 0, stream>>>(edge_src, edge_dst, E, odeg, ideg);

  // --- block scan of in-degree + norms (sn, dn) fused ---
  scan_block_kernel<<<NB, SCAN_B, 0, stream>>>(ideg, odeg, sn, dn,
                                               offsets, bsum, N);
  // ideg dead after scan_block: overwrite with W fragment tables
  stage_wfrag_kernel<<<2, 256, 0, stream>>>(W1, W2, Wg);

  // --- prescaled bf16 copy of x (needs sn) ---
  {
    int nquads = N * DIM / 4;
    convert_prescale_kernel<<<(nquads + 255) / 256, 256, 0, stream>>>(
        x, sn, xb_raw, nquads);
  }

  // --- fused top-scan + add ---
  scan_add_kernel<<<(N + 511) / 512, 512, 0, stream>>>(offsets, bsum, NB, N, E);

  // --- binned CSR build (binned overwrites odeg region — dead by now) ---
  bin_scatter_kernel<<<SCHUNKS, 512, 0, stream>>>(edge_src, edge_dst, offsets,
                                                  bin_cursor, binned, E);
  fill_binned_kernel<<<NBINS, 512, 0, stream>>>(binned, offsets, csr_src);

  const int fb = 1024;   // 4 blocks/CU, grid-stride ~6 batches/wave

  // --- layer 1: xb -> h1b (bf16, prescaled by sn; overwrites binned) ---
  fused_layer_kernel<true, __hip_bfloat16><<<fb, 256, 0, stream>>>(
      xb, csr_src, offsets, sn, dn, Wg, b1, h1b, N);

  // --- layer 2: h1b -> out (fp32) ---
  fused_layer_kernel<false, float><<<fb, 256, 0, stream>>>(
      h1b, csr_src, offsets, sn, dn, Wg + 8192, b2, out, N);
}

// Round 14
// 221.042 us; speedup vs baseline: 1.5272x; 1.5272x over previous
//
#include <hip/hip_runtime.h>
#include <hip/hip_bf16.h>

#define N_NODES 100000
#define DIM 64
#define SCAN_B 256

#define RANGE_NODES 50000   // node-range per histogram block (50KB LDS bytes)
#define HWORDS 12500        // RANGE_NODES/4 packed-byte words
#define HCHUNKS 64          // edge chunks per (array,range)
#define SCHUNKS 256         // edge chunks for bin scatter (full CU coverage)
#define BINSZ 512           // dst nodes per bin
#define NBINS 196           // ceil(N_NODES/BINSZ)

#define NBATCH 6250         // 100000 / 16 node-batches (exact)

typedef __attribute__((ext_vector_type(8))) short short8v;
typedef __attribute__((ext_vector_type(4))) float float4v;

// ---------------------------------------------------------------------------
// Packed-byte histogram (R12-verified): blocks [0,128) = src, [128,256) = dst.
// 1024 threads + int4 loads. LDS atomics only — R13 proved random GLOBAL
// atomics cost a full HBM line each (99.8 MB writes, 135us) on MI355X's
// non-cross-coherent per-XCD L2s.
// ---------------------------------------------------------------------------
__global__ __launch_bounds__(1024) void hist_kernel(
    const int* __restrict__ src, const int* __restrict__ dst, int nkeys,
    unsigned int* __restrict__ partials) {
  __shared__ unsigned int h[HWORDS];
  int which = blockIdx.x >> 7;             // 0 = src, 1 = dst
  int local = blockIdx.x & 127;
  int range = local >> 6;
  int chunk = local & 63;
  const int* keys = which ? dst : src;
  int lo = range * RANGE_NODES;
  for (int i = threadIdx.x; i < HWORDS; i += 1024) h[i] = 0;
  __syncthreads();
  int per = (((nkeys + HCHUNKS - 1) / HCHUNKS) + 3) & ~3;   // 25000 for E=1.6M
  int beg = chunk * per;
  int end = min(beg + per, nkeys);
  int n4 = (end > beg) ? ((end - beg) >> 2) : 0;
  const int4* k4 = (const int4*)(keys + beg);
  for (int i = threadIdx.x; i < n4; i += 1024) {
    int4 kv = k4[i];
    int a = kv.x - lo, b = kv.y - lo, c = kv.z - lo, d = kv.w - lo;
    if ((unsigned)a < (unsigned)RANGE_NODES)
      atomicAdd(&h[a >> 2], 1u << ((a & 3) * 8));
    if ((unsigned)b < (unsigned)RANGE_NODES)
      atomicAdd(&h[b >> 2], 1u << ((b & 3) * 8));
    if ((unsigned)c < (unsigned)RANGE_NODES)
      atomicAdd(&h[c >> 2], 1u << ((c & 3) * 8));
    if ((unsigned)d < (unsigned)RANGE_NODES)
      atomicAdd(&h[d >> 2], 1u << ((d & 3) * 8));
  }
  for (int i = beg + (n4 << 2) + threadIdx.x; i < end; i += 1024) {
    int k = keys[i] - lo;
    if ((unsigned)k < (unsigned)RANGE_NODES)
      atomicAdd(&h[k >> 2], 1u << ((k & 3) * 8));
  }
  __syncthreads();
  unsigned int* outp = partials + (size_t)blockIdx.x * HWORDS;
  for (int i = threadIdx.x; i < HWORDS; i += 1024) outp[i] = h[i];
}

// ---------------------------------------------------------------------------
// Sum 64 chunk-partials per word, unpack bytes -> sn / dn / ideg.
// ---------------------------------------------------------------------------
__global__ __launch_bounds__(256) void reduce_norm_kernel(
    const unsigned int* __restrict__ ps, const unsigned int* __restrict__ pd,
    float* __restrict__ sn, float* __restrict__ dn, int* __restrict__ ideg) {
  int w = blockIdx.x * 256 + threadIdx.x;
  if (w >= 2 * (N_NODES / 4)) return;
  int is_dst = (w >= N_NODES / 4);
  int lw = is_dst ? w - N_NODES / 4 : w;
  const unsigned int* p = is_dst ? pd : ps;
  int r = lw / HWORDS, wr = lw % HWORDS;
  const unsigned int* base = p + (size_t)(r * HCHUNKS) * HWORDS + wr;
  unsigned int s0 = 0, s1 = 0, s2 = 0, s3 = 0;
  for (int c = 0; c < HCHUNKS; ++c) {
    unsigned int v = base[(size_t)c * HWORDS];
    s0 += v & 255u; s1 += (v >> 8) & 255u; s2 += (v >> 16) & 255u; s3 += v >> 24;
  }
  unsigned int d[4] = {s0, s1, s2, s3};
  int n0 = r * RANGE_NODES + wr * 4;
#pragma unroll
  for (int j = 0; j < 4; ++j) {
    int n = n0 + j;
    float f = (d[j] > 0) ? rsqrtf((float)d[j]) : 0.0f;
    if (is_dst) { dn[n] = f; ideg[n] = (int)d[j]; }
    else        { sn[n] = f; }
  }
}

// ---------------------------------------------------------------------------
// xb[n][k] = bf16( x[n][k] * sn[n] )  — prescaled bf16 gather operand.
// ---------------------------------------------------------------------------
__global__ __launch_bounds__(256) void convert_prescale_kernel(
    const float* __restrict__ x, const float* __restrict__ sn,
    unsigned int* __restrict__ xb2, int nquads) {
  int i = blockIdx.x * 256 + threadIdx.x;
  if (i >= nquads) return;
  float s = sn[i >> 4];                       // node = (i*4)/64
  float4 v = ((const float4*)x)[i];
  __hip_bfloat162 a = __float22bfloat162_rn(make_float2(v.x * s, v.y * s));
  __hip_bfloat162 b = __float22bfloat162_rn(make_float2(v.z * s, v.w * s));
  unsigned int wa, wb;
  __builtin_memcpy(&wa, &a, 4);
  __builtin_memcpy(&wb, &b, 4);
  ((uint2*)xb2)[i] = make_uint2(wa, wb);
}

// ---------------------------------------------------------------------------
// Block-level exclusive scan of in-degree.
// ---------------------------------------------------------------------------
__global__ __launch_bounds__(SCAN_B) void scan_block_kernel(
    const int* __restrict__ in, int* __restrict__ out,
    int* __restrict__ bsum, int n) {
  __shared__ int s[SCAN_B];
  int t = threadIdx.x;
  int i = blockIdx.x * SCAN_B + t;
  int v = (i < n) ? in[i] : 0;
  s[t] = v;
  __syncthreads();
  for (int off = 1; off < SCAN_B; off <<= 1) {
    int add = (t >= off) ? s[t - off] : 0;
    __syncthreads();
    s[t] += add;
    __syncthreads();
  }
  if (i < n) out[i] = s[t] - v;
  if (t == SCAN_B - 1) bsum[blockIdx.x] = s[t];
}

// ---------------------------------------------------------------------------
// Fused top-scan + add (R13-verified, atomic-free): each block re-scans the
// 391 block sums in LDS, then applies the prefix. Removes scan_top launch.
// ---------------------------------------------------------------------------
__global__ __launch_bounds__(512) void scan_add_kernel(
    int* __restrict__ out, const int* __restrict__ bsum, int nb, int n,
    int total) {
  __shared__ int s[512];
  __shared__ int ex[512];
  int t = threadIdx.x;
  int v = (t < nb) ? bsum[t] : 0;
  s[t] = v;
  __syncthreads();
  for (int off = 1; off < 512; off <<= 1) {
    int add = (t >= off) ? s[t - off] : 0;
    __syncthreads();
    s[t] += add;
    __syncthreads();
  }
  ex[t] = s[t] - v;
  __syncthreads();
  int i = blockIdx.x * 512 + t;
  if (i < n) out[i] += ex[i >> 8];          // SCAN_B == 256
  if (i == 0) out[n] = total;
}

// ---------------------------------------------------------------------------
// Partition edges into NBINS dst-bins (R12-verified: 512 thr, int4 loads).
// ---------------------------------------------------------------------------
__global__ __launch_bounds__(512) void bin_scatter_kernel(
    const int* __restrict__ src, const int* __restrict__ dst,
    const int* __restrict__ offsets, int* __restrict__ bin_cursor,
    int2* __restrict__ binned, int E) {
  __shared__ int cnt[NBINS];
  __shared__ int base[NBINS];
  int t = threadIdx.x;
  for (int i = t; i < NBINS; i += 512) cnt[i] = 0;
  __syncthreads();
  int per = (((E + SCHUNKS - 1) / SCHUNKS) + 3) & ~3;   // 6252 for E=1.6M
  int beg = blockIdx.x * per;
  int end = min(beg + per, E);
  int n4 = (end > beg) ? ((end - beg) >> 2) : 0;
  const int4* d4 = (const int4*)(dst + beg);
  const int4* s4 = (const int4*)(src + beg);
  for (int i = t; i < n4; i += 512) {
    int4 dv = d4[i];
    atomicAdd(&cnt[dv.x >> 9], 1);
    atomicAdd(&cnt[dv.y >> 9], 1);
    atomicAdd(&cnt[dv.z >> 9], 1);
    atomicAdd(&cnt[dv.w >> 9], 1);
  }
  for (int i = beg + (n4 << 2) + t; i < end; i += 512)
    atomicAdd(&cnt[dst[i] >> 9], 1);
  __syncthreads();
  for (int i = t; i < NBINS; i += 512) {
    base[i] = offsets[i << 9] + atomicAdd(&bin_cursor[i], cnt[i]);
    cnt[i] = 0;
  }
  __syncthreads();
  for (int i = t; i < n4; i += 512) {
    int4 sv = s4[i];
    int4 dv = d4[i];
    int b0 = dv.x >> 9, r0 = atomicAdd(&cnt[b0], 1);
    binned[base[b0] + r0] = make_int2(sv.x, dv.x);
    int b1 = dv.y >> 9, r1 = atomicAdd(&cnt[b1], 1);
    binned[base[b1] + r1] = make_int2(sv.y, dv.y);
    int b2 = dv.z >> 9, r2 = atomicAdd(&cnt[b2], 1);
    binned[base[b2] + r2] = make_int2(sv.z, dv.z);
    int b3 = dv.w >> 9, r3 = atomicAdd(&cnt[b3], 1);
    binned[base[b3] + r3] = make_int2(sv.w, dv.w);
  }
  for (int i = beg + (n4 << 2) + t; i < end; i += 512) {
    int s = src[i], d = dst[i];
    int b = d >> 9;
    int r = atomicAdd(&cnt[b], 1);
    binned[base[b] + r] = make_int2(s, d);
  }
}

// ---------------------------------------------------------------------------
// CSR fill, one block per bin (R12-verified: 512 threads).
// ---------------------------------------------------------------------------
__global__ __launch_bounds__(512) void fill_binned_kernel(
    const int2* __restrict__ binned, const int* __restrict__ offsets,
    int* __restrict__ csr_src) {
  __shared__ int cur[BINSZ];
  __shared__ int offs[BINSZ];
  int b = blockIdx.x;
  int t = threadIdx.x;
  int lo = b << 9;
  for (int i = t; i < BINSZ; i += 512) {
    cur[i] = 0;
    offs[i] = offsets[min(lo + i, N_NODES)];
  }
  __syncthreads();
  int w0 = offsets[lo];
  int w1 = offsets[min(lo + BINSZ, N_NODES)];
  for (int e = w0 + t; e < w1; e += 512) {
    int2 sd = binned[e];
    int r = atomicAdd(&cur[sd.y - lo], 1);
    csr_src[offs[sd.y - lo] + r] = sd.x;
  }
}

// ---------------------------------------------------------------------------
// bf16 helpers (proven numerics).
// ---------------------------------------------------------------------------
__device__ __forceinline__ float bf_lo(unsigned int u) {
  unsigned int x = u << 16; float f; __builtin_memcpy(&f, &x, 4); return f;
}
__device__ __forceinline__ float bf_hi(unsigned int u) {
  unsigned int x = u & 0xffff0000u; float f; __builtin_memcpy(&f, &x, 4); return f;
}
__device__ __forceinline__ unsigned short bf16bits(float f) {
  __hip_bfloat16 h = __float2bfloat16(f);
  unsigned short u; __builtin_memcpy(&u, &h, 2); return u;
}
// (x,y) f32 -> packed hi bf16x2 (truncated) + packed lo bf16x2 (residual, RNE)
__device__ __forceinline__ void cvt_pair_hl(float x, float y,
                                            unsigned int& hi, unsigned int& lo) {
  unsigned int u0, u1;
  __builtin_memcpy(&u0, &x, 4);
  __builtin_memcpy(&u1, &y, 4);
  unsigned int h0 = u0 & 0xffff0000u, h1 = u1 & 0xffff0000u;
  hi = (h0 >> 16) | h1;
  float hf0, hf1;
  __builtin_memcpy(&hf0, &h0, 4);
  __builtin_memcpy(&hf1, &h1, 4);
  __hip_bfloat162 l2 = __float22bfloat162_rn(make_float2(x - hf0, y - hf1));
  __builtin_memcpy(&lo, &l2, 4);
}

// ---------------------------------------------------------------------------
// Pre-stage W as hi/lo bf16 B-fragments into GLOBAL (16 KiB per table).
// Layout: entry e = ((hl*4 + nt)*2 + kt)*64 + lane, 8 shorts each.
// k = kt*32 + (lane>>4)*8 + j, c = nt*16 + (lane&15)  (proven layout).
// ---------------------------------------------------------------------------
__global__ __launch_bounds__(256) void stage_wfrag_kernel(
    const float* __restrict__ W1, const float* __restrict__ W2,
    short* __restrict__ Wg) {
  const float* W = blockIdx.x ? W2 : W1;
  short* outp = Wg + blockIdx.x * 8192;
  int t = threadIdx.x;
  for (int e = t; e < 1024; e += 256) {
    int lidx = e & 63;
    int f = e >> 6;                       // 0..15
    int ktv = f & 1, ntv = (f >> 1) & 3, hl = f >> 3;
#pragma unroll
    for (int j = 0; j < 8; ++j) {
      int k = ktv * 32 + (lidx >> 4) * 8 + j;
      int c = ntv * 16 + (lidx & 15);
      float w = W[k * DIM + c];
      unsigned short hb = bf16bits(w);
      short val;
      if (hl == 0) {
        val = (short)hb;
      } else {
        unsigned int hx = (unsigned int)hb << 16;
        float hf; __builtin_memcpy(&hf, &hx, 4);
        val = (short)bf16bits(w - hf);
      }
      outp[e * 8 + j] = val;
    }
  }
}

// ---------------------------------------------------------------------------
// Fused layer v9 (champion, replay-stable: R7/R8/R11/R12 all passed): 256-thr
// blocks, wave per 16-node batch, grid-stride. BYTE-IDENTICAL to R12.
// ---------------------------------------------------------------------------
template <bool PRESCALE, typename OUT_T>
__device__ __forceinline__ void epilogue_nt(
    float4v acc, float bv, int nb16, int kq, int lane, float snb,
    OUT_T* __restrict__ out, int nt) {
  int col = nt * 16 + (lane & 15);
#pragma unroll
  for (int r = 0; r < 4; ++r) {
    int node = nb16 + kq * 4 + r;          // C/D row = (lane>>4)*4 + reg
    float o = fmaxf(acc[r] + bv, 0.0f);
    if (PRESCALE) {
      o = o * __shfl(snb, kq * 4 + r);
      out[(long)node * DIM + col] = (OUT_T)__float2bfloat16(o);
    } else {
      out[(long)node * DIM + col] = (OUT_T)o;
    }
  }
}

template <bool PRESCALE, typename OUT_T>
__global__ __launch_bounds__(256, 4) void fused_layer_kernel(
    const __hip_bfloat16* __restrict__ xb, const int* __restrict__ csr_src,
    const int* __restrict__ offsets, const float* __restrict__ sn,
    const float* __restrict__ dn, const short* __restrict__ Wg,
    const float* __restrict__ bias, OUT_T* __restrict__ out, int N) {
  __shared__ __align__(16) float Astage[4][16][64];   // 16 KiB

  int t = threadIdx.x;
  int lane = t & 63;
  int wslot = t >> 6;          // 0..3
  int g = lane >> 4;           // edge sub-slot / MFMA k-group 0..3
  int q = lane & 15;           // feature quad / A-row (node-in-batch)

  float bias_nt[4];
#pragma unroll
  for (int nt = 0; nt < 4; ++nt) bias_nt[nt] = bias[nt * 16 + q];

  const uint2* __restrict__ xr = (const uint2*)xb;   // one row = 16 uint2
  const short8v* __restrict__ wfrag = (const short8v*)Wg;
  char* abase = (char*)&Astage[wslot][0][0];         // 256 B per node row

  int nwaves = gridDim.x * 4;
  for (int nb = blockIdx.x * 4 + wslot; nb < NBATCH; nb += nwaves) {
    asm volatile("" ::: "memory");   // no cross-batch hoist of W-frag loads
    int nb16 = nb * 16;
    int offv = offsets[nb16 + min(lane, 16)];
    float dnv = dn[nb16 + q];
    float snb = PRESCALE ? sn[nb16 + q] : 0.0f;

    // ---- gather 16 nodes (proven structure) ----
    for (int ni = 0; ni < 16; ++ni) {
      int beg = __shfl(offv, ni);
      int end = __shfl(offv, ni + 1);
      float a0 = 0.f, a1 = 0.f, a2 = 0.f, a3 = 0.f;
      for (int base = beg; base < end; base += 16) {
        int j0 = base + g;
        int jm = end - 1;
        bool p0 = j0 < end, p1 = j0 + 4 < end, p2 = j0 + 8 < end,
             p3 = j0 + 12 < end;
        int s0 = csr_src[min(j0, jm)];
        int s1 = csr_src[min(j0 + 4, jm)];
        int s2 = csr_src[min(j0 + 8, jm)];
        int s3 = csr_src[min(j0 + 12, jm)];
        uint2 v0 = make_uint2(0u, 0u), v1 = v0, v2 = v0, v3 = v0;
        if (p0) v0 = xr[(size_t)s0 * 16 + q];
        if (p1) v1 = xr[(size_t)s1 * 16 + q];
        if (p2) v2 = xr[(size_t)s2 * 16 + q];
        if (p3) v3 = xr[(size_t)s3 * 16 + q];
        a0 += bf_lo(v0.x); a1 += bf_hi(v0.x); a2 += bf_lo(v0.y); a3 += bf_hi(v0.y);
        a0 += bf_lo(v1.x); a1 += bf_hi(v1.x); a2 += bf_lo(v1.y); a3 += bf_hi(v1.y);
        a0 += bf_lo(v2.x); a1 += bf_hi(v2.x); a2 += bf_lo(v2.y); a3 += bf_hi(v2.y);
        a0 += bf_lo(v3.x); a1 += bf_hi(v3.x); a2 += bf_lo(v3.y); a3 += bf_hi(v3.y);
      }
      a0 += __shfl_xor(a0, 16); a1 += __shfl_xor(a1, 16);
      a2 += __shfl_xor(a2, 16); a3 += __shfl_xor(a3, 16);
      a0 += __shfl_xor(a0, 32); a1 += __shfl_xor(a1, 32);
      a2 += __shfl_xor(a2, 32); a3 += __shfl_xor(a3, 32);

      float dnw = __shfl(dnv, ni);
      if (lane < 16) {
        // quad q of node ni at swizzled slot (both sides use same involution)
        int woff = ni * 256 + ((lane * 16) ^ ((ni & 15) << 4));
        *(float4*)(abase + woff) =
            make_float4(a0 * dnw, a1 * dnw, a2 * dnw, a3 * dnw);
      }
    }

    // ---- project: read A rows (same-wave LDS, lgkm-ordered), 24 MFMA ----
    float4v acc0 = {0.f, 0.f, 0.f, 0.f}, acc1 = acc0, acc2 = acc0, acc3 = acc0;
#pragma unroll
    for (int kt = 0; kt < 2; ++kt) {
      int o1 = kt * 128 + g * 32;     // feats kt*32+8g.. of node q
      float4 fa = *(const float4*)(abase + q * 256 + (o1 ^ (q << 4)));
      float4 fb = *(const float4*)(abase + q * 256 + ((o1 + 16) ^ (q << 4)));
      union { unsigned int w[4]; short8v v; } Uh, Ul;
      cvt_pair_hl(fa.x, fa.y, Uh.w[0], Ul.w[0]);
      cvt_pair_hl(fa.z, fa.w, Uh.w[1], Ul.w[1]);
      cvt_pair_hl(fb.x, fb.y, Uh.w[2], Ul.w[2]);
      cvt_pair_hl(fb.z, fb.w, Uh.w[3], Ul.w[3]);
      short8v ahi = Uh.v, alo = Ul.v;
#define PROJ_NT(NT, ACC)                                                      \
      {                                                                       \
        short8v bh = wfrag[(((NT) * 2) + kt) * 64 + lane];                    \
        short8v bl = wfrag[(((4 + (NT)) * 2) + kt) * 64 + lane];              \
        ACC = __builtin_amdgcn_mfma_f32_16x16x32_bf16(ahi, bh, ACC, 0, 0, 0); \
        ACC = __builtin_amdgcn_mfma_f32_16x16x32_bf16(alo, bh, ACC, 0, 0, 0); \
        ACC = __builtin_amdgcn_mfma_f32_16x16x32_bf16(ahi, bl, ACC, 0, 0, 0); \
      }
      PROJ_NT(0, acc0)
      PROJ_NT(1, acc1)
      PROJ_NT(2, acc2)
      PROJ_NT(3, acc3)
#undef PROJ_NT
    }

    float snbv = PRESCALE ? snb : 0.0f;
    epilogue_nt<PRESCALE, OUT_T>(acc0, bias_nt[0], nb16, g, lane, snbv, out, 0);
    epilogue_nt<PRESCALE, OUT_T>(acc1, bias_nt[1], nb16, g, lane, snbv, out, 1);
    epilogue_nt<PRESCALE, OUT_T>(acc2, bias_nt[2], nb16, g, lane, snbv, out, 2);
    epilogue_nt<PRESCALE, OUT_T>(acc3, bias_nt[3], nb16, g, lane, snbv, out, 3);
  }
}

extern "C" void kernel_launch(void* const* d_in, const int* in_sizes, int n_in,
                              void* d_out, int out_size, void* d_ws, size_t ws_size,
                              hipStream_t stream) {
  const float* x        = (const float*)d_in[0];
  const int*   edge_src = (const int*)d_in[1];
  const int*   edge_dst = (const int*)d_in[2];
  const float* W1       = (const float*)d_in[3];
  const float* b1       = (const float*)d_in[4];
  const float* W2       = (const float*)d_in[5];
  const float* b2       = (const float*)d_in[6];
  float* out = (float*)d_out;

  const int E = in_sizes[1];
  const int N = N_NODES;
  const int NB = (N + SCAN_B - 1) / SCAN_B;   // 391

  // Workspace (4B units), ~33.6 MB total. regionB time-shared:
  //   partials (hist..reduce) -> binned (bin_scatter..fill) -> h1b (layers)
  // ideg time-shared: degree counts (reduce..scan_block) -> W frag tables.
  float* sn         = (float*)d_ws;                  // N
  float* dn         = sn + N;                        // N
  int*   ideg       = (int*)(dn + N);                // N
  int*   offsets    = ideg + N;                      // N+1
  int*   bsum       = offsets + (N + 1);             // 512
  int*   bin_cursor = bsum + 512;                    // 256
  int*   csr_src    = bin_cursor + 256;              // E
  unsigned int* xb_raw = (unsigned int*)(csr_src + E);       // N*DIM/2 (12.8MB)
  unsigned int* regionB = xb_raw + (size_t)N * DIM / 2;      // 12.8MB
  unsigned int* partials = regionB;                          // 256*HWORDS
  int2*  binned   = (int2*)regionB;                  // E int2
  __hip_bfloat16* xb  = (__hip_bfloat16*)xb_raw;
  __hip_bfloat16* h1b = (__hip_bfloat16*)regionB;
  short* Wg = (short*)ideg;                          // 2 x 8192 shorts (32 KB)

  hipMemsetAsync(bin_cursor, 0, 256 * sizeof(int), stream);

  // --- degrees + norms (LDS-histogram path, no global atomics) ---
  hist_kernel<<<256, 1024, 0, stream>>>(edge_src, edge_dst, E, partials);
  reduce_norm_kernel<<<(2 * (N / 4) + 255) / 256, 256, 0, stream>>>(
      partials, partials + (size_t)128 * HWORDS, sn, dn, ideg);

  // --- prescaled bf16 copy of x ---
  {
    int nquads = N * DIM / 4;
    convert_prescale_kernel<<<(nquads + 255) / 256, 256, 0, stream>>>(
        x, sn, xb_raw, nquads);
  }

  // --- offsets = exclusive scan of in-degree ---
  scan_block_kernel<<<NB, SCAN_B, 0, stream>>>(ideg, offsets, bsum, N);
  // ideg dead after scan_block: overwrite with W fragment tables
  stage_wfrag_kernel<<<2, 256, 0, stream>>>(W1, W2, Wg);
  // fused top-scan + add (R13-verified, atomic-free)
  scan_add_kernel<<<(N + 511) / 512, 512, 0, stream>>>(offsets, bsum, NB, N, E);

  // --- binned CSR build (overwrites partials region — dead after reduce) ---
  bin_scatter_kernel<<<SCHUNKS, 512, 0, stream>>>(edge_src, edge_dst, offsets,
                                                  bin_cursor, binned, E);
  fill_binned_kernel<<<NBINS, 512, 0, stream>>>(binned, offsets, csr_src);

  const int fb = 1024;   // 4 blocks/CU, grid-stride ~6 batches/wave

  // --- layer 1: xb -> h1b (bf16, prescaled by sn; overwrites binned) ---
  fused_layer_kernel<true, __hip_bfloat16><<<fb, 256, 0, stream>>>(
      xb, csr_src, offsets, sn, dn, Wg, b1, h1b, N);

  // --- layer 2: h1b -> out (fp32) ---
  fused_layer_kernel<false, float><<<fb, 256, 0, stream>>>(
      h1b, csr_src, offsets, sn, dn, Wg + 8192, b2, out, N);
}

// Round 15
// 209.806 us; speedup vs baseline: 1.6090x; 1.0536x over previous
//
#include <hip/hip_runtime.h>
#include <hip/hip_bf16.h>

#define N_NODES 100000
#define DIM 64

#define RANGE_NODES 50000   // node-range per histogram block (50KB LDS bytes)
#define HWORDS 12500        // RANGE_NODES/4 packed-byte words
#define HCHUNKS 64          // edge chunks per (array,range)
#define SCHUNKS 256         // edge chunks for bin scatter (full CU coverage)
#define BINSZ 512           // dst nodes per bin
#define NBINS 196           // ceil(N_NODES/BINSZ)

#define NBATCH 6250         // 100000 / 16 node-batches (exact)

typedef __attribute__((ext_vector_type(8))) short short8v;
typedef __attribute__((ext_vector_type(4))) float float4v;

// ---------------------------------------------------------------------------
// Packed-byte histogram (R12-verified): blocks [0,128) = src, [128,256) = dst.
// 1024 threads + int4 loads. LDS atomics only — R13 proved random GLOBAL
// atomics cost a full HBM line each (99.8 MB writes, 135us) on MI355X's
// non-cross-coherent per-XCD L2s.
// ---------------------------------------------------------------------------
__global__ __launch_bounds__(1024) void hist_kernel(
    const int* __restrict__ src, const int* __restrict__ dst, int nkeys,
    unsigned int* __restrict__ partials) {
  __shared__ unsigned int h[HWORDS];
  int which = blockIdx.x >> 7;             // 0 = src, 1 = dst
  int local = blockIdx.x & 127;
  int range = local >> 6;
  int chunk = local & 63;
  const int* keys = which ? dst : src;
  int lo = range * RANGE_NODES;
  for (int i = threadIdx.x; i < HWORDS; i += 1024) h[i] = 0;
  __syncthreads();
  int per = (((nkeys + HCHUNKS - 1) / HCHUNKS) + 3) & ~3;   // 25000 for E=1.6M
  int beg = chunk * per;
  int end = min(beg + per, nkeys);
  int n4 = (end > beg) ? ((end - beg) >> 2) : 0;
  const int4* k4 = (const int4*)(keys + beg);
  for (int i = threadIdx.x; i < n4; i += 1024) {
    int4 kv = k4[i];
    int a = kv.x - lo, b = kv.y - lo, c = kv.z - lo, d = kv.w - lo;
    if ((unsigned)a < (unsigned)RANGE_NODES)
      atomicAdd(&h[a >> 2], 1u << ((a & 3) * 8));
    if ((unsigned)b < (unsigned)RANGE_NODES)
      atomicAdd(&h[b >> 2], 1u << ((b & 3) * 8));
    if ((unsigned)c < (unsigned)RANGE_NODES)
      atomicAdd(&h[c >> 2], 1u << ((c & 3) * 8));
    if ((unsigned)d < (unsigned)RANGE_NODES)
      atomicAdd(&h[d >> 2], 1u << ((d & 3) * 8));
  }
  for (int i = beg + (n4 << 2) + threadIdx.x; i < end; i += 1024) {
    int k = keys[i] - lo;
    if ((unsigned)k < (unsigned)RANGE_NODES)
      atomicAdd(&h[k >> 2], 1u << ((k & 3) * 8));
  }
  __syncthreads();
  unsigned int* outp = partials + (size_t)blockIdx.x * HWORDS;
  for (int i = threadIdx.x; i < HWORDS; i += 1024) outp[i] = h[i];
}

// ---------------------------------------------------------------------------
// Fused reduce + norms + block-scan (R15).
//   Blocks [0,98): src half — sn only.
//   Blocks [98,196): dst half — dn + in-block exclusive scan of 1024
//     in-degrees (node = 4*lw exactly, monotonic; the 50000 range boundary
//     is 4-aligned so a thread's quad never splits). ideg never materialized;
//     scan_block launch and its round-trip removed. Block 0 zeroes
//     bin_cursor (replaces the hipMemsetAsync dispatch).
// ---------------------------------------------------------------------------
__global__ __launch_bounds__(256) void reduce_norm_scan_kernel(
    const unsigned int* __restrict__ ps, const unsigned int* __restrict__ pd,
    float* __restrict__ sn, float* __restrict__ dn,
    int* __restrict__ offsets, int* __restrict__ bsum,
    int* __restrict__ bin_cursor) {
  __shared__ int s[256];
  int t = threadIdx.x;
  int b = blockIdx.x;
  if (b == 0) bin_cursor[t] = 0;            // NBINS = 196 <= 256
  int is_dst = (b >= 98);
  int lw = (is_dst ? b - 98 : b) * 256 + t;
  bool valid = lw < 25000;
  const unsigned int* p = is_dst ? pd : ps;
  unsigned int d0 = 0, d1 = 0, d2 = 0, d3 = 0;
  int n0 = 0;
  if (valid) {
    int r = lw / HWORDS, wr = lw % HWORDS;
    const unsigned int* base = p + (size_t)(r * HCHUNKS) * HWORDS + wr;
    for (int c = 0; c < HCHUNKS; ++c) {
      unsigned int v = base[(size_t)c * HWORDS];
      d0 += v & 255u; d1 += (v >> 8) & 255u;
      d2 += (v >> 16) & 255u; d3 += v >> 24;
    }
    n0 = r * RANGE_NODES + wr * 4;          // == 4*lw
    float4 f;
    f.x = d0 ? rsqrtf((float)d0) : 0.0f;
    f.y = d1 ? rsqrtf((float)d1) : 0.0f;
    f.z = d2 ? rsqrtf((float)d2) : 0.0f;
    f.w = d3 ? rsqrtf((float)d3) : 0.0f;
    if (is_dst) *(float4*)(dn + n0) = f;
    else        *(float4*)(sn + n0) = f;
  }
  if (!is_dst) return;                      // src blocks: no barriers below

  int v = valid ? (int)(d0 + d1 + d2 + d3) : 0;
  s[t] = v;
  __syncthreads();
  for (int off = 1; off < 256; off <<= 1) {
    int add = (t >= off) ? s[t - off] : 0;
    __syncthreads();
    s[t] += add;
    __syncthreads();
  }
  if (valid) {
    int pfx = s[t] - v;
    int4 o;
    o.x = pfx;
    o.y = pfx + (int)d0;
    o.z = pfx + (int)(d0 + d1);
    o.w = pfx + (int)(d0 + d1 + d2);
    *(int4*)(offsets + n0) = o;
  }
  if (t == 255) bsum[b - 98] = s[255];      // one entry per 1024 nodes
}

// ---------------------------------------------------------------------------
// xb[n][k] = bf16( x[n][k] * sn[n] )  — prescaled bf16 gather operand.
// ---------------------------------------------------------------------------
__global__ __launch_bounds__(256) void convert_prescale_kernel(
    const float* __restrict__ x, const float* __restrict__ sn,
    unsigned int* __restrict__ xb2, int nquads) {
  int i = blockIdx.x * 256 + threadIdx.x;
  if (i >= nquads) return;
  float s = sn[i >> 4];                       // node = (i*4)/64
  float4 v = ((const float4*)x)[i];
  __hip_bfloat162 a = __float22bfloat162_rn(make_float2(v.x * s, v.y * s));
  __hip_bfloat162 b = __float22bfloat162_rn(make_float2(v.z * s, v.w * s));
  unsigned int wa, wb;
  __builtin_memcpy(&wa, &a, 4);
  __builtin_memcpy(&wb, &b, 4);
  ((uint2*)xb2)[i] = make_uint2(wa, wb);
}

// ---------------------------------------------------------------------------
// Fused top-scan + add (R13-verified; R15: 1024-node granularity, nb = 98).
// ---------------------------------------------------------------------------
__global__ __launch_bounds__(512) void scan_add_kernel(
    int* __restrict__ out, const int* __restrict__ bsum, int nb, int n,
    int total) {
  __shared__ int s[512];
  __shared__ int ex[512];
  int t = threadIdx.x;
  int v = (t < nb) ? bsum[t] : 0;
  s[t] = v;
  __syncthreads();
  for (int off = 1; off < 512; off <<= 1) {
    int add = (t >= off) ? s[t - off] : 0;
    __syncthreads();
    s[t] += add;
    __syncthreads();
  }
  ex[t] = s[t] - v;
  __syncthreads();
  int i = blockIdx.x * 512 + t;
  if (i < n) out[i] += ex[i >> 10];         // 1024-node scan blocks
  if (i == 0) out[n] = total;
}

// ---------------------------------------------------------------------------
// Partition edges into NBINS dst-bins (R12-verified: 512 thr, int4 loads).
// ---------------------------------------------------------------------------
__global__ __launch_bounds__(512) void bin_scatter_kernel(
    const int* __restrict__ src, const int* __restrict__ dst,
    const int* __restrict__ offsets, int* __restrict__ bin_cursor,
    int2* __restrict__ binned, int E) {
  __shared__ int cnt[NBINS];
  __shared__ int base[NBINS];
  int t = threadIdx.x;
  for (int i = t; i < NBINS; i += 512) cnt[i] = 0;
  __syncthreads();
  int per = (((E + SCHUNKS - 1) / SCHUNKS) + 3) & ~3;   // 6252 for E=1.6M
  int beg = blockIdx.x * per;
  int end = min(beg + per, E);
  int n4 = (end > beg) ? ((end - beg) >> 2) : 0;
  const int4* d4 = (const int4*)(dst + beg);
  const int4* s4 = (const int4*)(src + beg);
  for (int i = t; i < n4; i += 512) {
    int4 dv = d4[i];
    atomicAdd(&cnt[dv.x >> 9], 1);
    atomicAdd(&cnt[dv.y >> 9], 1);
    atomicAdd(&cnt[dv.z >> 9], 1);
    atomicAdd(&cnt[dv.w >> 9], 1);
  }
  for (int i = beg + (n4 << 2) + t; i < end; i += 512)
    atomicAdd(&cnt[dst[i] >> 9], 1);
  __syncthreads();
  for (int i = t; i < NBINS; i += 512) {
    base[i] = offsets[i << 9] + atomicAdd(&bin_cursor[i], cnt[i]);
    cnt[i] = 0;
  }
  __syncthreads();
  for (int i = t; i < n4; i += 512) {
    int4 sv = s4[i];
    int4 dv = d4[i];
    int b0 = dv.x >> 9, r0 = atomicAdd(&cnt[b0], 1);
    binned[base[b0] + r0] = make_int2(sv.x, dv.x);
    int b1 = dv.y >> 9, r1 = atomicAdd(&cnt[b1], 1);
    binned[base[b1] + r1] = make_int2(sv.y, dv.y);
    int b2 = dv.z >> 9, r2 = atomicAdd(&cnt[b2], 1);
    binned[base[b2] + r2] = make_int2(sv.z, dv.z);
    int b3 = dv.w >> 9, r3 = atomicAdd(&cnt[b3], 1);
    binned[base[b3] + r3] = make_int2(sv.w, dv.w);
  }
  for (int i = beg + (n4 << 2) + t; i < end; i += 512) {
    int s = src[i], d = dst[i];
    int b = d >> 9;
    int r = atomicAdd(&cnt[b], 1);
    binned[base[b] + r] = make_int2(s, d);
  }
}

// ---------------------------------------------------------------------------
// CSR fill, one block per bin (R12-verified: 512 threads).
// ---------------------------------------------------------------------------
__global__ __launch_bounds__(512) void fill_binned_kernel(
    const int2* __restrict__ binned, const int* __restrict__ offsets,
    int* __restrict__ csr_src) {
  __shared__ int cur[BINSZ];
  __shared__ int offs[BINSZ];
  int b = blockIdx.x;
  int t = threadIdx.x;
  int lo = b << 9;
  for (int i = t; i < BINSZ; i += 512) {
    cur[i] = 0;
    offs[i] = offsets[min(lo + i, N_NODES)];
  }
  __syncthreads();
  int w0 = offsets[lo];
  int w1 = offsets[min(lo + BINSZ, N_NODES)];
  for (int e = w0 + t; e < w1; e += 512) {
    int2 sd = binned[e];
    int r = atomicAdd(&cur[sd.y - lo], 1);
    csr_src[offs[sd.y - lo] + r] = sd.x;
  }
}

// ---------------------------------------------------------------------------
// bf16 helpers (proven numerics).
// ---------------------------------------------------------------------------
__device__ __forceinline__ float bf_lo(unsigned int u) {
  unsigned int x = u << 16; float f; __builtin_memcpy(&f, &x, 4); return f;
}
__device__ __forceinline__ float bf_hi(unsigned int u) {
  unsigned int x = u & 0xffff0000u; float f; __builtin_memcpy(&f, &x, 4); return f;
}
__device__ __forceinline__ unsigned short bf16bits(float f) {
  __hip_bfloat16 h = __float2bfloat16(f);
  unsigned short u; __builtin_memcpy(&u, &h, 2); return u;
}
// (x,y) f32 -> packed hi bf16x2 (truncated) + packed lo bf16x2 (residual, RNE)
__device__ __forceinline__ void cvt_pair_hl(float x, float y,
                                            unsigned int& hi, unsigned int& lo) {
  unsigned int u0, u1;
  __builtin_memcpy(&u0, &x, 4);
  __builtin_memcpy(&u1, &y, 4);
  unsigned int h0 = u0 & 0xffff0000u, h1 = u1 & 0xffff0000u;
  hi = (h0 >> 16) | h1;
  float hf0, hf1;
  __builtin_memcpy(&hf0, &h0, 4);
  __builtin_memcpy(&hf1, &h1, 4);
  __hip_bfloat162 l2 = __float22bfloat162_rn(make_float2(x - hf0, y - hf1));
  __builtin_memcpy(&lo, &l2, 4);
}

// ---------------------------------------------------------------------------
// Pre-stage W as hi/lo bf16 B-fragments into GLOBAL (16 KiB per table).
// Layout: entry e = ((hl*4 + nt)*2 + kt)*64 + lane, 8 shorts each.
// k = kt*32 + (lane>>4)*8 + j, c = nt*16 + (lane&15)  (proven layout).
// ---------------------------------------------------------------------------
__global__ __launch_bounds__(256) void stage_wfrag_kernel(
    const float* __restrict__ W1, const float* __restrict__ W2,
    short* __restrict__ Wg) {
  const float* W = blockIdx.x ? W2 : W1;
  short* outp = Wg + blockIdx.x * 8192;
  int t = threadIdx.x;
  for (int e = t; e < 1024; e += 256) {
    int lidx = e & 63;
    int f = e >> 6;                       // 0..15
    int ktv = f & 1, ntv = (f >> 1) & 3, hl = f >> 3;
#pragma unroll
    for (int j = 0; j < 8; ++j) {
      int k = ktv * 32 + (lidx >> 4) * 8 + j;
      int c = ntv * 16 + (lidx & 15);
      float w = W[k * DIM + c];
      unsigned short hb = bf16bits(w);
      short val;
      if (hl == 0) {
        val = (short)hb;
      } else {
        unsigned int hx = (unsigned int)hb << 16;
        float hf; __builtin_memcpy(&hf, &hx, 4);
        val = (short)bf16bits(w - hf);
      }
      outp[e * 8 + j] = val;
    }
  }
}

// ---------------------------------------------------------------------------
// Fused layer v9 (champion, replay-stable: R7/R8/R11/R12/R14): 256-thr
// blocks, wave per 16-node batch, grid-stride. BYTE-IDENTICAL to R14.
// ---------------------------------------------------------------------------
template <bool PRESCALE, typename OUT_T>
__device__ __forceinline__ void epilogue_nt(
    float4v acc, float bv, int nb16, int kq, int lane, float snb,
    OUT_T* __restrict__ out, int nt) {
  int col = nt * 16 + (lane & 15);
#pragma unroll
  for (int r = 0; r < 4; ++r) {
    int node = nb16 + kq * 4 + r;          // C/D row = (lane>>4)*4 + reg
    float o = fmaxf(acc[r] + bv, 0.0f);
    if (PRESCALE) {
      o = o * __shfl(snb, kq * 4 + r);
      out[(long)node * DIM + col] = (OUT_T)__float2bfloat16(o);
    } else {
      out[(long)node * DIM + col] = (OUT_T)o;
    }
  }
}

template <bool PRESCALE, typename OUT_T>
__global__ __launch_bounds__(256, 4) void fused_layer_kernel(
    const __hip_bfloat16* __restrict__ xb, const int* __restrict__ csr_src,
    const int* __restrict__ offsets, const float* __restrict__ sn,
    const float* __restrict__ dn, const short* __restrict__ Wg,
    const float* __restrict__ bias, OUT_T* __restrict__ out, int N) {
  __shared__ __align__(16) float Astage[4][16][64];   // 16 KiB

  int t = threadIdx.x;
  int lane = t & 63;
  int wslot = t >> 6;          // 0..3
  int g = lane >> 4;           // edge sub-slot / MFMA k-group 0..3
  int q = lane & 15;           // feature quad / A-row (node-in-batch)

  float bias_nt[4];
#pragma unroll
  for (int nt = 0; nt < 4; ++nt) bias_nt[nt] = bias[nt * 16 + q];

  const uint2* __restrict__ xr = (const uint2*)xb;   // one row = 16 uint2
  const short8v* __restrict__ wfrag = (const short8v*)Wg;
  char* abase = (char*)&Astage[wslot][0][0];         // 256 B per node row

  int nwaves = gridDim.x * 4;
  for (int nb = blockIdx.x * 4 + wslot; nb < NBATCH; nb += nwaves) {
    asm volatile("" ::: "memory");   // no cross-batch hoist of W-frag loads
    int nb16 = nb * 16;
    int offv = offsets[nb16 + min(lane, 16)];
    float dnv = dn[nb16 + q];
    float snb = PRESCALE ? sn[nb16 + q] : 0.0f;

    // ---- gather 16 nodes (proven structure) ----
    for (int ni = 0; ni < 16; ++ni) {
      int beg = __shfl(offv, ni);
      int end = __shfl(offv, ni + 1);
      float a0 = 0.f, a1 = 0.f, a2 = 0.f, a3 = 0.f;
      for (int base = beg; base < end; base += 16) {
        int j0 = base + g;
        int jm = end - 1;
        bool p0 = j0 < end, p1 = j0 + 4 < end, p2 = j0 + 8 < end,
             p3 = j0 + 12 < end;
        int s0 = csr_src[min(j0, jm)];
        int s1 = csr_src[min(j0 + 4, jm)];
        int s2 = csr_src[min(j0 + 8, jm)];
        int s3 = csr_src[min(j0 + 12, jm)];
        uint2 v0 = make_uint2(0u, 0u), v1 = v0, v2 = v0, v3 = v0;
        if (p0) v0 = xr[(size_t)s0 * 16 + q];
        if (p1) v1 = xr[(size_t)s1 * 16 + q];
        if (p2) v2 = xr[(size_t)s2 * 16 + q];
        if (p3) v3 = xr[(size_t)s3 * 16 + q];
        a0 += bf_lo(v0.x); a1 += bf_hi(v0.x); a2 += bf_lo(v0.y); a3 += bf_hi(v0.y);
        a0 += bf_lo(v1.x); a1 += bf_hi(v1.x); a2 += bf_lo(v1.y); a3 += bf_hi(v1.y);
        a0 += bf_lo(v2.x); a1 += bf_hi(v2.x); a2 += bf_lo(v2.y); a3 += bf_hi(v2.y);
        a0 += bf_lo(v3.x); a1 += bf_hi(v3.x); a2 += bf_lo(v3.y); a3 += bf_hi(v3.y);
      }
      a0 += __shfl_xor(a0, 16); a1 += __shfl_xor(a1, 16);
      a2 += __shfl_xor(a2, 16); a3 += __shfl_xor(a3, 16);
      a0 += __shfl_xor(a0, 32); a1 += __shfl_xor(a1, 32);
      a2 += __shfl_xor(a2, 32); a3 += __shfl_xor(a3, 32);

      float dnw = __shfl(dnv, ni);
      if (lane < 16) {
        // quad q of node ni at swizzled slot (both sides use same involution)
        int woff = ni * 256 + ((lane * 16) ^ ((ni & 15) << 4));
        *(float4*)(abase + woff) =
            make_float4(a0 * dnw, a1 * dnw, a2 * dnw, a3 * dnw);
      }
    }

    // ---- project: read A rows (same-wave LDS, lgkm-ordered), 24 MFMA ----
    float4v acc0 = {0.f, 0.f, 0.f, 0.f}, acc1 = acc0, acc2 = acc0, acc3 = acc0;
#pragma unroll
    for (int kt = 0; kt < 2; ++kt) {
      int o1 = kt * 128 + g * 32;     // feats kt*32+8g.. of node q
      float4 fa = *(const float4*)(abase + q * 256 + (o1 ^ (q << 4)));
      float4 fb = *(const float4*)(abase + q * 256 + ((o1 + 16) ^ (q << 4)));
      union { unsigned int w[4]; short8v v; } Uh, Ul;
      cvt_pair_hl(fa.x, fa.y, Uh.w[0], Ul.w[0]);
      cvt_pair_hl(fa.z, fa.w, Uh.w[1], Ul.w[1]);
      cvt_pair_hl(fb.x, fb.y, Uh.w[2], Ul.w[2]);
      cvt_pair_hl(fb.z, fb.w, Uh.w[3], Ul.w[3]);
      short8v ahi = Uh.v, alo = Ul.v;
#define PROJ_NT(NT, ACC)                                                      \
      {                                                                       \
        short8v bh = wfrag[(((NT) * 2) + kt) * 64 + lane];                    \
        short8v bl = wfrag[(((4 + (NT)) * 2) + kt) * 64 + lane];              \
        ACC = __builtin_amdgcn_mfma_f32_16x16x32_bf16(ahi, bh, ACC, 0, 0, 0); \
        ACC = __builtin_amdgcn_mfma_f32_16x16x32_bf16(alo, bh, ACC, 0, 0, 0); \
        ACC = __builtin_amdgcn_mfma_f32_16x16x32_bf16(ahi, bl, ACC, 0, 0, 0); \
      }
      PROJ_NT(0, acc0)
      PROJ_NT(1, acc1)
      PROJ_NT(2, acc2)
      PROJ_NT(3, acc3)
#undef PROJ_NT
    }

    float snbv = PRESCALE ? snb : 0.0f;
    epilogue_nt<PRESCALE, OUT_T>(acc0, bias_nt[0], nb16, g, lane, snbv, out, 0);
    epilogue_nt<PRESCALE, OUT_T>(acc1, bias_nt[1], nb16, g, lane, snbv, out, 1);
    epilogue_nt<PRESCALE, OUT_T>(acc2, bias_nt[2], nb16, g, lane, snbv, out, 2);
    epilogue_nt<PRESCALE, OUT_T>(acc3, bias_nt[3], nb16, g, lane, snbv, out, 3);
  }
}

extern "C" void kernel_launch(void* const* d_in, const int* in_sizes, int n_in,
                              void* d_out, int out_size, void* d_ws, size_t ws_size,
                              hipStream_t stream) {
  const float* x        = (const float*)d_in[0];
  const int*   edge_src = (const int*)d_in[1];
  const int*   edge_dst = (const int*)d_in[2];
  const float* W1       = (const float*)d_in[3];
  const float* b1       = (const float*)d_in[4];
  const float* W2       = (const float*)d_in[5];
  const float* b2       = (const float*)d_in[6];
  float* out = (float*)d_out;

  const int E = in_sizes[1];
  const int N = N_NODES;

  // Workspace (4B units), ~33.6 MB total. regionB time-shared:
  //   partials (hist..reduce) -> binned (bin_scatter..fill) -> h1b (layers)
  // Wg scratch uses the old ideg slot (ideg never materialized in R15).
  float* sn         = (float*)d_ws;                  // N
  float* dn         = sn + N;                        // N
  int*   wg_slot    = (int*)(dn + N);                // N (scratch; Wg 32 KB)
  int*   offsets    = wg_slot + N;                   // N+1
  int*   bsum       = offsets + (N + 1);             // 512 (98 used)
  int*   bin_cursor = bsum + 512;                    // 256
  int*   csr_src    = bin_cursor + 256;              // E
  unsigned int* xb_raw = (unsigned int*)(csr_src + E);       // N*DIM/2 (12.8MB)
  unsigned int* regionB = xb_raw + (size_t)N * DIM / 2;      // 12.8MB
  unsigned int* partials = regionB;                          // 256*HWORDS
  int2*  binned   = (int2*)regionB;                  // E int2
  __hip_bfloat16* xb  = (__hip_bfloat16*)xb_raw;
  __hip_bfloat16* h1b = (__hip_bfloat16*)regionB;
  short* Wg = (short*)wg_slot;                       // 2 x 8192 shorts (32 KB)

  // --- degrees (LDS-histogram path, no global atomics) ---
  hist_kernel<<<256, 1024, 0, stream>>>(edge_src, edge_dst, E, partials);

  // --- fused: norms + in-block offset scan + bin_cursor zero ---
  reduce_norm_scan_kernel<<<196, 256, 0, stream>>>(
      partials, partials + (size_t)128 * HWORDS, sn, dn, offsets, bsum,
      bin_cursor);

  // --- W fragment tables (depends only on W1/W2) ---
  stage_wfrag_kernel<<<2, 256, 0, stream>>>(W1, W2, Wg);

  // --- prescaled bf16 copy of x (needs sn) ---
  {
    int nquads = N * DIM / 4;
    convert_prescale_kernel<<<(nquads + 255) / 256, 256, 0, stream>>>(
        x, sn, xb_raw, nquads);
  }

  // --- fused top-scan + add (nb = 98, 1024-node granularity) ---
  scan_add_kernel<<<(N + 511) / 512, 512, 0, stream>>>(offsets, bsum, 98, N, E);

  // --- binned CSR build (overwrites partials region — dead after reduce) ---
  bin_scatter_kernel<<<SCHUNKS, 512, 0, stream>>>(edge_src, edge_dst, offsets,
                                                  bin_cursor, binned, E);
  fill_binned_kernel<<<NBINS, 512, 0, stream>>>(binned, offsets, csr_src);

  const int fb = 1024;   // 4 blocks/CU, grid-stride ~6 batches/wave

  // --- layer 1: xb -> h1b (bf16, prescaled by sn; overwrites binned) ---
  fused_layer_kernel<true, __hip_bfloat16><<<fb, 256, 0, stream>>>(
      xb, csr_src, offsets, sn, dn, Wg, b1, h1b, N);

  // --- layer 2: h1b -> out (fp32) ---
  fused_layer_kernel<false, float><<<fb, 256, 0, stream>>>(
      h1b, csr_src, offsets, sn, dn, Wg + 8192, b2, out, N);
}